// Round 1
// baseline (3751.474 us; speedup 1.0000x reference)
//
#include <hip/hip_runtime.h>
#include <math.h>

#define BB 256
#define TIN 32
#define TOUT 29
#define VDEC 72
#define EDIM 256
#define HDIM 256
#define DD 6
#define BH (BB*HDIM)

typedef unsigned short u16;
typedef unsigned int u32;
typedef __bf16 bf16x8 __attribute__((ext_vector_type(8)));
typedef float f32x4 __attribute__((ext_vector_type(4)));
typedef u16 u16x8 __attribute__((ext_vector_type(8)));

// fast transcendental helpers (overflow-safe forms)
__device__ __forceinline__ float sigmf(float x){ return 1.0f/(1.0f+__expf(-x)); }
__device__ __forceinline__ float tanhf_fast(float x){ return 1.0f - 2.0f/(1.0f+__expf(2.0f*x)); }
__device__ __forceinline__ u16 f2bf(float f){
  u32 u = __builtin_bit_cast(u32, f);
  u32 r = (u + 0x7fffu + ((u>>16)&1u)) >> 16;   // RNE; inputs finite
  return (u16)r;
}
__device__ __forceinline__ float bf2f(u16 s){
  u32 u = ((u32)s)<<16; return __builtin_bit_cast(float, u);
}
__device__ __forceinline__ bf16x8 ldbf8(const u16* p){
  u16x8 t = *(const u16x8*)p; return __builtin_bit_cast(bf16x8, t);
}
__device__ __forceinline__ f32x4 mfma16(bf16x8 a, bf16x8 b, f32x4 c){
  return __builtin_amdgcn_mfma_f32_16x16x32_bf16(a, b, c, 0, 0, 0);
}

// ---------------- init ----------------
__global__ void fill_zero_u32(u32* __restrict__ p, int n){
  int i = blockIdx.x*256 + threadIdx.x;
  if (i < n) p[i] = 0u;
}

__global__ void init_out_kernel(float* __restrict__ out, int n){
  int i = blockIdx.x*256 + threadIdx.x;
  if (i >= n) return;
  float v = 0.0f;
  if (i < BB*VDEC && (i % VDEC) == 1) v = 1.0f;   // pred0 one-hot
  out[i] = v;
}

// bias2d[p][m][g] = (sum_l W2[m,l]) * b1[g] + b2[m]   (p: 0=a, 1=h, 2=c)
__global__ void bias2d_kernel(const float* __restrict__ W2a, const float* __restrict__ b1a, const float* __restrict__ b2a,
                              const float* __restrict__ W2h, const float* __restrict__ b1h, const float* __restrict__ b2h,
                              const float* __restrict__ W2c, const float* __restrict__ b1c, const float* __restrict__ b2c,
                              float* __restrict__ outp){
  int g = threadIdx.x;
  const float* W2[3] = {W2a, W2h, W2c};
  const float* b1[3] = {b1a, b1h, b1c};
  const float* b2[3] = {b2a, b2h, b2c};
  for (int p = 0; p < 3; p++)
    for (int m = 0; m < 6; m++){
      float s = 0.f;
      for (int l = 0; l < 6; l++) s += W2[p][m*6+l];
      outp[p*1536 + m*256 + g] = s * b1[p][g] + b2[p][m];
    }
}

__global__ void embed_enc_kernel(const int* __restrict__ input, const float* __restrict__ enc_emb,
                                 u16* __restrict__ x_emb){
  int i = blockIdx.x*256 + threadIdx.x;       // TIN*BB*EDIM threads
  int e = i & 255, b = (i >> 8) & 255, t = i >> 16;
  x_emb[i] = f2bf(enc_emb[(size_t)input[b*TIN + t]*EDIM + e]);
}

// pack fp32 weights -> bf16, row-permuted so each stage block's 64 rows are contiguous.
// dst row' = (d*16+ht)*64 + q*16 + hh  <->  src gate row g = q*256 + ht*16 + hh of dir d.
__global__ void pack_w_kernel(const float* __restrict__ Wih, const float* __restrict__ Whh,
                              u16* __restrict__ dst, int K1, int K){
  int k = blockIdx.x*256 + threadIdx.x;
  int row = blockIdx.y;
  int d = row >> 10, rr = row & 1023;
  int ht = rr >> 6, r = rr & 63;
  int g = (r>>4)*256 + ht*16 + (r&15);
  float v;
  if (k < K1) v = Wih[((size_t)d*1024 + g)*K1 + k];
  else        v = Whh[((size_t)d*1024 + g)*256 + (k - K1)];
  dst[(size_t)row*K + k] = f2bf(v);
}

// fused decoder stage-0 weights: W'[g, 0:512] = sum_o Wih0[g,o]*attn_W[o, 0:512]; cols 512:768 = Whh
__global__ void pack_wfused_kernel(const float* __restrict__ Wih0, const float* __restrict__ attn_W,
                                   const float* __restrict__ Whh, u16* __restrict__ dst){
  int k = blockIdx.x*256 + threadIdx.x;       // grid.x = 3 -> k in 0..767
  int row = blockIdx.y;                        // 0..2047
  int d = row >> 10, rr = row & 1023;
  int ht = rr >> 6, r = rr & 63;
  int g = (r>>4)*256 + ht*16 + (r&15);
  float v;
  if (k >= 512) v = Whh[((size_t)d*1024 + g)*256 + (k - 512)];
  else {
    const float* wr = Wih0 + ((size_t)d*1024 + g)*256;
    float s = 0.f;
    #pragma unroll 4
    for (int o = 0; o < 256; o++) s += wr[o] * attn_W[(size_t)o*512 + k];
    v = s;
  }
  dst[(size_t)row*768 + k] = f2bf(v);
}

// fused decoder stage-0 bias: b'[d,g] = dec_b[l=0,d,g] + sum_o Wih0[d,g,o]*attn_b[o]
__global__ void biasfold_kernel(const float* __restrict__ Wih0, const float* __restrict__ attn_b,
                                const float* __restrict__ dec_b, float* __restrict__ outb){
  int i = blockIdx.x*256 + threadIdx.x;  // 2048
  int d = i >> 10, g = i & 1023;
  const float* wr = Wih0 + ((size_t)d*1024 + g)*256;
  float s = dec_b[d*1024 + g];
  #pragma unroll 4
  for (int o = 0; o < 256; o++) s += wr[o]*attn_b[o];
  outb[i] = s;
}

// out[t,m,b,h] = sum_l W2[m,l] * in[t,l,b,h]  (fp32, in-place safe)
__global__ void mix_kernel(const float* __restrict__ inp, float* __restrict__ outp,
                           const float* __restrict__ W2, int n){
  int i = blockIdx.x*256 + threadIdx.x;
  if (i >= n) return;
  int h = i & 255, b = (i >> 8) & 255, t = i >> 16;
  size_t base = ((size_t)t*6)*BH + (size_t)b*256 + h;
  float v[6];
  #pragma unroll
  for (int l = 0; l < 6; l++) v[l] = inp[base + (size_t)l*BH];
  #pragma unroll
  for (int m = 0; m < 6; m++){
    float s = 0.f;
    #pragma unroll
    for (int l = 0; l < 6; l++) s += W2[m*6+l]*v[l];
    outp[base + (size_t)m*BH] = s;
  }
}

// C[M,256] = A[M,256] @ W[256,256]^T + bias2d[(row/256)%6][n]  (fp32; C and/or Cbf nullable)
__global__ __launch_bounds__(256) void gemmN256_kernel(const float* __restrict__ A, float* __restrict__ C,
                                                       const float* __restrict__ W,
                                                       const float* __restrict__ bias2d,
                                                       u16* __restrict__ Cbf){
  __shared__ float As[32][33];
  __shared__ float Ws[256][34];
  int tid = threadIdx.x;
  int m_base = blockIdx.x * 32;
  int rg = tid >> 5, cg = tid & 31;
  float acc[4][8];
  #pragma unroll
  for (int i=0;i<4;i++)
    #pragma unroll
    for (int j=0;j<8;j++) acc[i][j]=0.f;
  for (int k0 = 0; k0 < 256; k0 += 32){
    #pragma unroll
    for (int p=0;p<4;p++) As[rg + p*8][cg] = A[(size_t)(m_base + rg + p*8)*256 + k0 + cg];
    #pragma unroll
    for (int p=0;p<32;p++) Ws[rg + p*8][cg] = W[(size_t)(rg + p*8)*256 + k0 + cg];
    __syncthreads();
    #pragma unroll
    for (int kk=0; kk<32; kk++){
      float a[4], w[8];
      #pragma unroll
      for (int i=0;i<4;i++) a[i] = As[rg*4+i][kk];
      #pragma unroll
      for (int j=0;j<8;j++) w[j] = Ws[cg*8+j][kk];
      #pragma unroll
      for (int i=0;i<4;i++)
        #pragma unroll
        for (int j=0;j<8;j++) acc[i][j] += a[i]*w[j];
    }
    __syncthreads();
  }
  #pragma unroll
  for (int i=0;i<4;i++){
    int row = m_base + rg*4 + i;
    int bm = (row >> 8) % 6;
    #pragma unroll
    for (int j=0;j<8;j++){
      float v = acc[i][j] + bias2d[bm*256 + cg*8 + j];
      if (C)   C[(size_t)row*256 + cg*8 + j] = v;
      if (Cbf) Cbf[(size_t)row*256 + cg*8 + j] = f2bf(v);
    }
  }
}

// ---------------- fused LSTM stage, bf16 MFMA ----------------
// grid (8, 32): x -> 32-batch tile; y -> d = y>>4, ht = y&15.
// Pipelined: double-buffered LDS, 2-deep register prefetch, ONE barrier per K-step.
// lda == K1 for every call site, so it's folded into the template parameter.
template<int K1>
__global__ __launch_bounds__(256) void lstm_stage_mfma(
    const u16* __restrict__ inp,
    const u16* __restrict__ Wpk,
    const float* __restrict__ bias_l,
    const u16* __restrict__ hR, u16* __restrict__ hW,
    float* __restrict__ cBuf, u16* __restrict__ inp_out,
    float* __restrict__ h_all_t, int l){
  constexpr int K = K1 + 256;
  constexpr int NIT = K >> 6;
  __shared__ __align__(16) u16 As[2][32][72];
  __shared__ __align__(16) u16 Ws[2][64][72];
  __shared__ float Gt[4][32][17];
  int tid = threadIdx.x;
  int m_base = blockIdx.x*32;
  int d = blockIdx.y >> 4, ht = blockIdx.y & 15;
  int idx = 2*l + d;
  const u16* Wblk = Wpk + (size_t)((d*16+ht)*64)*K;
  int q = tid >> 6, lane = tid & 63;
  int ar = tid >> 3, kp = (tid & 7)*8;
  const u16* aRow  = inp + (size_t)(m_base+ar)*K1 + kp;
  const u16* hRow  = hR + (size_t)idx*BH + (size_t)(m_base+ar)*HDIM + kp - K1;
  const u16* wRow0 = Wblk + (size_t)ar*K + kp;
  const u16* wRow1 = Wblk + (size_t)(ar+32)*K + kp;
  uint4 aP[2], w0P[2], w1P[2];
  #pragma unroll
  for (int pf = 0; pf < 2; pf++){
    int c0 = pf*64;
    const u16* ap = (c0 + kp < K1) ? aRow : hRow;
    aP[pf]  = *(const uint4*)(ap + c0);
    w0P[pf] = *(const uint4*)(wRow0 + c0);
    w1P[pf] = *(const uint4*)(wRow1 + c0);
  }
  f32x4 acc0 = {0.f,0.f,0.f,0.f}, acc1 = {0.f,0.f,0.f,0.f};
  #pragma unroll
  for (int i = 0; i < NIT; i++){
    int p = i & 1;
    *(uint4*)&As[p][ar][kp]     = aP[p];
    *(uint4*)&Ws[p][ar][kp]     = w0P[p];
    *(uint4*)&Ws[p][ar+32][kp]  = w1P[p];
    int c0n = (i+2) << 6;
    if (c0n < K){
      const u16* ap = (c0n + kp < K1) ? aRow : hRow;
      aP[p]  = *(const uint4*)(ap + c0n);
      w0P[p] = *(const uint4*)(wRow0 + c0n);
      w1P[p] = *(const uint4*)(wRow1 + c0n);
    }
    __syncthreads();   // buf[p] written by all; prior readers of buf[p] finished (barrier i-1)
    #pragma unroll
    for (int kh = 0; kh < 2; kh++){
      int kb = kh*32 + (lane>>4)*8;
      bf16x8 a0 = ldbf8(&As[p][lane & 15][kb]);
      bf16x8 a1 = ldbf8(&As[p][16 + (lane & 15)][kb]);
      bf16x8 bq = ldbf8(&Ws[p][q*16 + (lane & 15)][kb]);
      acc0 = mfma16(a0, bq, acc0);
      acc1 = mfma16(a1, bq, acc1);
    }
  }
  int hh = lane & 15, rq = lane >> 4;
  #pragma unroll
  for (int r = 0; r < 4; r++){
    Gt[q][rq*4 + r][hh]      = acc0[r];
    Gt[q][16 + rq*4 + r][hh] = acc1[r];
  }
  __syncthreads();
  const float* bias = bias_l + d*1024;
  #pragma unroll
  for (int it = 0; it < 2; it++){
    int id = tid + it*256;
    int bb = id >> 4, h2 = id & 15;
    int b = m_base + bb, h = ht*16 + h2;
    float iv = Gt[0][bb][h2] + bias[h];
    float fv = Gt[1][bb][h2] + bias[256 + h];
    float gv = Gt[2][bb][h2] + bias[512 + h];
    float ov = Gt[3][bb][h2] + bias[768 + h];
    size_t off = (size_t)idx*BH + (size_t)b*HDIM + h;
    float cold = cBuf[off];
    float cc = sigmf(fv)*cold + sigmf(iv)*tanhf_fast(gv);
    float hv = sigmf(ov)*tanhf_fast(cc);
    cBuf[off] = cc;
    u16 hb = f2bf(hv);
    hW[off] = hb;
    inp_out[(size_t)b*512 + d*HDIM + h] = hb;
    if (h_all_t) h_all_t[off] = hv;
  }
}

// ---------------- attention ctx + fc(prev step) + token embed (fused), grid 512 --------
// blocks 0..255: ctx for batch row b=blk  -> cat[b, 256:512]
// blocks 256..511: logits(step-1) from top -> out row `step`; token select; emb -> cat[b, 0:256]
__global__ void attn_tok_kernel(const u16* __restrict__ hR, const u16* __restrict__ eo,
                                u16* __restrict__ cat, const int* __restrict__ tf,
                                float* __restrict__ attn_out, int step,
                                const int* __restrict__ target, float* __restrict__ outp,
                                const float* __restrict__ dec_emb, const u16* __restrict__ top,
                                const float* __restrict__ fc_W, const float* __restrict__ fc_b){
  int blk = blockIdx.x, tid = threadIdx.x;
  __shared__ float s[512];
  __shared__ float lg[VDEC];
  __shared__ int tokS;
  if (blk < 256){
    int b = blk, hc = tid;
    bool wa = (tf[0] == 0);
    float acc = 0.f;
    for (int d = 0; d < DD; d++){
      float hv = bf2f(hR[(size_t)d*BH + (size_t)b*256 + hc]);
      const u16* ep = eo + (size_t)d*BH + (size_t)b*256 + hc;
      float se = 0.f, ac = 0.f;
      #pragma unroll 8
      for (int t = 0; t < TIN; t++){
        float ev = bf2f(ep[(size_t)t*(DD*BH)]);
        float e = __expf(hv*ev);          // bounded args; softmax ratio exact
        se += e; ac += e*ev;
      }
      acc += ac/se;
      if (wa){
        float inv = 1.f/se;
        for (int t = 0; t < TIN; t++){
          float ev = bf2f(ep[(size_t)t*(DD*BH)]);
          atomicAdd(&attn_out[(((size_t)(step+1)*TIN + t)*DD + d)*BB + b], __expf(hv*ev)*inv);
        }
      }
    }
    cat[(size_t)b*512 + 256 + hc] = f2bf(acc*(1.0f/6.0f));
  } else {
    int b = blk - 256;
    if (step > 0){
      s[tid]       = bf2f(top[(size_t)b*512 + tid]);
      s[tid + 256] = bf2f(top[(size_t)b*512 + 256 + tid]);
      __syncthreads();
      if (tid < VDEC){
        float a = fc_b[tid];
        #pragma unroll 4
        for (int k = 0; k < 512; k++) a += s[k]*fc_W[(size_t)tid*512 + k];
        outp[((size_t)step*BB + b)*VDEC + tid] = a;
        lg[tid] = a;
      }
      __syncthreads();
    }
    int tok;
    if (tf[0]) tok = target[b*TOUT + step];
    else if (step == 0) tok = 1;
    else {
      if (tid == 0){
        int bi = 0; float bv = lg[0];
        for (int v = 1; v < VDEC; v++){ float x = lg[v]; if (x > bv){ bv = x; bi = v; } }
        tokS = bi;
      }
      __syncthreads();
      tok = tokS;
    }
    cat[(size_t)b*512 + tid] = f2bf(dec_emb[(size_t)tok*EDIM + tid]);
  }
}

// ---------------- fc head (only the final step) ----------------
__global__ void fc_kernel(const u16* __restrict__ top, const float* __restrict__ fc_W,
                          const float* __restrict__ fc_b, float* __restrict__ outp, int step){
  __shared__ float s[512];
  int b = blockIdx.x, tid = threadIdx.x;
  s[tid]       = bf2f(top[(size_t)b*512 + tid]);
  s[tid + 256] = bf2f(top[(size_t)b*512 + 256 + tid]);
  __syncthreads();
  if (tid < VDEC){
    float a = fc_b[tid];
    #pragma unroll 4
    for (int k = 0; k < 512; k++) a += s[k]*fc_W[(size_t)tid*512 + k];
    outp[((size_t)(step+1)*BB + b)*VDEC + tid] = a;
  }
}

// =====================================================================

extern "C" void kernel_launch(void* const* d_in, const int* in_sizes, int n_in,
                              void* d_out, int out_size, void* d_ws, size_t ws_size,
                              hipStream_t stream){
  (void)in_sizes; (void)n_in; (void)out_size; (void)ws_size;
  const int*   input    = (const int*)d_in[0];
  const int*   target   = (const int*)d_in[1];
  const int*   tf       = (const int*)d_in[2];
  const float* enc_emb  = (const float*)d_in[3];
  const float* dec_emb  = (const float*)d_in[4];
  const float* enc_Wih0 = (const float*)d_in[5];
  const float* enc_Wih1 = (const float*)d_in[6];
  const float* enc_Whh  = (const float*)d_in[7];
  const float* enc_b    = (const float*)d_in[8];
  const float* dec_Wih0 = (const float*)d_in[9];
  const float* dec_Wih1 = (const float*)d_in[10];
  const float* dec_Whh  = (const float*)d_in[11];
  const float* dec_b    = (const float*)d_in[12];
  const float* lin_h_W1 = (const float*)d_in[13];
  const float* lin_h_b1 = (const float*)d_in[14];
  const float* lin_h_W2 = (const float*)d_in[15];
  const float* lin_h_b2 = (const float*)d_in[16];
  const float* lin_c_W1 = (const float*)d_in[17];
  const float* lin_c_b1 = (const float*)d_in[18];
  const float* lin_c_W2 = (const float*)d_in[19];
  const float* lin_c_b2 = (const float*)d_in[20];
  const float* lin_a_W1 = (const float*)d_in[21];
  const float* lin_a_b1 = (const float*)d_in[22];
  const float* lin_a_W2 = (const float*)d_in[23];
  const float* lin_a_b2 = (const float*)d_in[24];
  const float* attn_W   = (const float*)d_in[25];
  const float* attn_b   = (const float*)d_in[26];
  const float* fc_W     = (const float*)d_in[27];
  const float* fc_b     = (const float*)d_in[28];
  float* out = (float*)d_out;

  char* base = (char*)d_ws;
  size_t off = 0;
  auto alloc = [&](size_t bytes)->char*{
    char* p = base + off; off += (bytes + 255) & ~(size_t)255; return p;
  };
  float* h_all  = (float*)alloc(sizeof(float)*(size_t)TIN*DD*BH);
  float* tmp6   = (float*)alloc(sizeof(float)*(size_t)DD*BH);
  float* dec_c  = (float*)alloc(sizeof(float)*(size_t)DD*BH);
  float* bias2d = (float*)alloc(sizeof(float)*3*6*256);
  // zero block: enc_hA (bf16) + enc_c (fp32), contiguous
  u16*   enc_hA = (u16*)alloc(sizeof(u16)*(size_t)DD*BH + sizeof(float)*(size_t)DD*BH);
  float* enc_c  = (float*)(enc_hA + (size_t)DD*BH);
  u16* enc_hB = (u16*)alloc(sizeof(u16)*(size_t)DD*BH);
  u16* dec_hA = (u16*)alloc(sizeof(u16)*(size_t)DD*BH);
  u16* dec_hB = (u16*)alloc(sizeof(u16)*(size_t)DD*BH);
  u16* x_emb  = (u16*)alloc(sizeof(u16)*(size_t)TIN*BB*EDIM);
  u16* bufA   = (u16*)alloc(sizeof(u16)*(size_t)BB*512);
  u16* bufB   = (u16*)alloc(sizeof(u16)*(size_t)BB*512);
  u16* cat    = (u16*)alloc(sizeof(u16)*(size_t)BB*512);       // [emb | ctx]
  u16* eo_bf  = (u16*)alloc(sizeof(u16)*(size_t)TIN*DD*BH);    // bf16 encoder_outputs
  u16* wp_e0  = (u16*)alloc(sizeof(u16)*(size_t)2048*512);
  u16* wp_e1  = (u16*)alloc(sizeof(u16)*(size_t)2048*768);
  u16* wp_e2  = (u16*)alloc(sizeof(u16)*(size_t)2048*768);
  u16* wp_d0f = (u16*)alloc(sizeof(u16)*(size_t)2048*768);     // fused attn_W . Wih0 | Whh
  u16* wp_d1  = (u16*)alloc(sizeof(u16)*(size_t)2048*768);
  u16* wp_d2  = (u16*)alloc(sizeof(u16)*(size_t)2048*768);
  float* fb0  = (float*)alloc(sizeof(float)*2048);             // fused stage-0 bias

  const int outn = TOUT*BB*VDEC + TOUT*TIN*DD*BB;
  init_out_kernel<<<(outn+255)/256, 256, 0, stream>>>(out, outn);
  fill_zero_u32<<<(DD*BH*6/4 + 255)/256, 256, 0, stream>>>((u32*)enc_hA, DD*BH*6/4);
  bias2d_kernel<<<1, 256, 0, stream>>>(lin_a_W2, lin_a_b1, lin_a_b2,
                                       lin_h_W2, lin_h_b1, lin_h_b2,
                                       lin_c_W2, lin_c_b1, lin_c_b2, bias2d);
  embed_enc_kernel<<<(TIN*BB*EDIM)/256, 256, 0, stream>>>(input, enc_emb, x_emb);
  pack_w_kernel<<<dim3(2,2048), 256, 0, stream>>>(enc_Wih0, enc_Whh,                       wp_e0, 256, 512);
  pack_w_kernel<<<dim3(3,2048), 256, 0, stream>>>(enc_Wih1, enc_Whh + 2*1024*256,          wp_e1, 512, 768);
  pack_w_kernel<<<dim3(3,2048), 256, 0, stream>>>(enc_Wih1 + (size_t)2*1024*512, enc_Whh + 4*1024*256, wp_e2, 512, 768);
  pack_wfused_kernel<<<dim3(3,2048), 256, 0, stream>>>(dec_Wih0, attn_W, dec_Whh,          wp_d0f);
  biasfold_kernel<<<8, 256, 0, stream>>>(dec_Wih0, attn_b, dec_b, fb0);
  pack_w_kernel<<<dim3(3,2048), 256, 0, stream>>>(dec_Wih1, dec_Whh + 2*1024*256,          wp_d1, 512, 768);
  pack_w_kernel<<<dim3(3,2048), 256, 0, stream>>>(dec_Wih1 + (size_t)2*1024*512, dec_Whh + 4*1024*256, wp_d2, 512, 768);

  dim3 sgrid(8, 32);
  // -------- encoder --------
  for (int t = 0; t < TIN; t++){
    const u16* hRb = (t & 1) ? enc_hB : enc_hA;
    u16*       hWb = (t & 1) ? enc_hA : enc_hB;
    float* hat = h_all + (size_t)t*DD*BH;
    lstm_stage_mfma<256><<<sgrid,256,0,stream>>>(x_emb + (size_t)t*BB*EDIM, wp_e0,
        enc_b,        hRb, hWb, enc_c, bufA, hat, 0);
    lstm_stage_mfma<512><<<sgrid,256,0,stream>>>(bufA, wp_e1,
        enc_b + 2048, hRb, hWb, enc_c, bufB, hat, 1);
    lstm_stage_mfma<512><<<sgrid,256,0,stream>>>(bufB, wp_e2,
        enc_b + 4096, hRb, hWb, enc_c, bufA, hat, 2);
  }
  // -------- bridges FIRST (need un-projected h_all[t=31]), then in-place a-projection --------
  mix_kernel<<<BH/256, 256, 0, stream>>>(h_all + (size_t)31*DD*BH, tmp6, lin_h_W2, BH);
  gemmN256_kernel<<<(DD*BB)/32, 256, 0, stream>>>(tmp6, nullptr, lin_h_W1, bias2d + 1536, dec_hA);
  mix_kernel<<<BH/256, 256, 0, stream>>>(enc_c, tmp6, lin_c_W2, BH);
  gemmN256_kernel<<<(DD*BB)/32, 256, 0, stream>>>(tmp6, dec_c, lin_c_W1, bias2d + 3072, nullptr);
  mix_kernel<<<(TIN*BH)/256, 256, 0, stream>>>(h_all, h_all, lin_a_W2, TIN*BH);
  gemmN256_kernel<<<(TIN*DD*BB)/32, 256, 0, stream>>>(h_all, nullptr, lin_a_W1, bias2d, eo_bf);

  // -------- decoder --------
  float* attn_out = out + (size_t)TOUT*BB*VDEC;
  for (int i = 0; i < TOUT-1; i++){
    const u16* hRb = (i & 1) ? dec_hB : dec_hA;
    u16*       hWb = (i & 1) ? dec_hA : dec_hB;
    attn_tok_kernel<<<512, 256, 0, stream>>>(hRb, eo_bf, cat, tf, attn_out, i,
                                             target, out, dec_emb, bufA, fc_W, fc_b);
    lstm_stage_mfma<512><<<sgrid,256,0,stream>>>(cat,  wp_d0f,
        fb0,          hRb, hWb, dec_c, bufA, nullptr, 0);
    lstm_stage_mfma<512><<<sgrid,256,0,stream>>>(bufA, wp_d1,
        dec_b + 2048, hRb, hWb, dec_c, bufB, nullptr, 1);
    lstm_stage_mfma<512><<<sgrid,256,0,stream>>>(bufB, wp_d2,
        dec_b + 4096, hRb, hWb, dec_c, bufA, nullptr, 2);
  }
  fc_kernel<<<BB, 256, 0, stream>>>(bufA, fc_W, fc_b, out, TOUT-2);
}